// Round 17
// baseline (188.927 us; speedup 1.0000x reference)
//
#include <hip/hip_runtime.h>
#include <hip/hip_bf16.h>
#include <math.h>

#define N_NODES 50000
#define N_EDGES 800000
#define IN_DIM  256
#define HID     32
#define HEADS   8
#define NCLS    40
#define NEG     0.2f
#define CAP1    128
#define CAP2    128

using short8  = __attribute__((ext_vector_type(8))) short;
using f32x4   = __attribute__((ext_vector_type(4))) float;
using floatx2 = __attribute__((ext_vector_type(2))) float;

__device__ __forceinline__ float leaky(float x) { return x >= 0.f ? x : NEG * x; }
__device__ __forceinline__ unsigned short f2b(float f) {
    unsigned int u = __float_as_uint(f);
    unsigned int r = (u + 0x7fffu + ((u >> 16) & 1u)) >> 16;
    return (unsigned short)r;
}
__device__ __forceinline__ float b2f(unsigned short h) {
    return __uint_as_float((unsigned int)h << 16);
}
__device__ __forceinline__ unsigned char f2e4m3(float v) {
    int p = __builtin_amdgcn_cvt_pk_fp8_f32(v, v, 0, false);
    return (unsigned char)(p & 0xff);
}

// Permuted fp8/bf16 channel storage: channel c = half*128 + ni*16 + csub
// stored at offset s = half*128 + csub*8 + ni.

// Fused: weight conversion (blocks 0..255) + Wl/Wr fold (block 256) + histogram+rank (rest)
__global__ void cvt_hist_k(const float* __restrict__ W1, const float* __restrict__ W2,
                           const float* __restrict__ al1, const float* __restrict__ ar1,
                           unsigned short* __restrict__ BTile, unsigned short* __restrict__ W2T,
                           unsigned short* __restrict__ wlr,
                           const int* __restrict__ dst, int* __restrict__ deg,
                           int* __restrict__ rank) {
    if (blockIdx.x < 256) {
        int n = blockIdx.x, k = threadIdx.x;
        BTile[(size_t)(k >> 5) * 8192 + n * 32 + (k & 31)] = f2b(W1[k * 256 + n]);
        if (n < 48) {
            int half = k >> 7, cs = (k & 127) >> 3, ni = k & 7;
            int ck = half * 128 + ni * 16 + cs;
            W2T[n * 256 + k] = (n < 40) ? f2b(W2[ck * 40 + n]) : (unsigned short)0;
        }
    } else if (blockIdx.x == 256) {
        int k = threadIdx.x;                      // 0..255
        const float* wrow = W1 + (size_t)k * 256;
#pragma unroll
        for (int h = 0; h < 8; h++) {
            float vl = 0.f, vr = 0.f;
#pragma unroll
            for (int d = 0; d < 32; d++) {
                float w = wrow[h * 32 + d];
                vl += w * al1[h * 32 + d];
                vr += w * ar1[h * 32 + d];
            }
            wlr[(size_t)(k >> 5) * 512 + h * 32 + (k & 31)]        = f2b(vl);
            wlr[(size_t)(k >> 5) * 512 + (8 + h) * 32 + (k & 31)]  = f2b(vr);
        }
    } else {
        int e4 = (blockIdx.x - 257) * 256 + threadIdx.x;
        if (e4 * 4 >= N_EDGES) return;
        int4 d = *reinterpret_cast<const int4*>(dst + e4 * 4);
        int4 rk;
        rk.x = atomicAdd(&deg[d.x], 1);
        rk.y = atomicAdd(&deg[d.y], 1);
        rk.z = atomicAdd(&deg[d.z], 1);
        rk.w = atomicAdd(&deg[d.w], 1);
        *reinterpret_cast<int4*>(rank + e4 * 4) = rk;
    }
}

// ---------------- GEMM1 (MFMA bf16, B direct from L2) + el1/er1 + scatter ------
// blocks [0, gblocks): GEMM1 64-row tiles (scheduled first)
// blocks [gblocks, ...): atomic-free scatter
__global__ __launch_bounds__(256) void gemm1_scatter_k(const float* __restrict__ A,
                                                       const unsigned short* __restrict__ BTile,
                                                       const unsigned short* __restrict__ wlr,
                                                       unsigned char* __restrict__ F8,
                                                       float* __restrict__ el,
                                                       float* __restrict__ er, int M,
                                                       int gblocks,
                                                       const int* __restrict__ src,
                                                       const int* __restrict__ dst,
                                                       const int* __restrict__ rank,
                                                       const int* __restrict__ offs,
                                                       int* __restrict__ ssorted) {
    __shared__ unsigned short Asm[2][64][40];
    if (blockIdx.x >= gblocks) {
        int e4 = (blockIdx.x - gblocks) * 256 + threadIdx.x;
        if (e4 * 4 >= N_EDGES) return;
        int4 d  = *reinterpret_cast<const int4*>(dst + e4 * 4);
        int4 sv = *reinterpret_cast<const int4*>(src + e4 * 4);
        int4 rk = *reinterpret_cast<const int4*>(rank + e4 * 4);
        __builtin_nontemporal_store(sv.x, &ssorted[offs[d.x] + rk.x]);
        __builtin_nontemporal_store(sv.y, &ssorted[offs[d.y] + rk.y]);
        __builtin_nontemporal_store(sv.z, &ssorted[offs[d.z] + rk.z]);
        __builtin_nontemporal_store(sv.w, &ssorted[offs[d.w] + rk.w]);
        return;
    }
    int t = threadIdx.x;
    int lane = t & 63, w = t >> 6;
    int wr = w >> 1, wc = w & 1;          // wave tile: 32 rows x 128 cols
    int m0 = blockIdx.x * 64;
    int rsub = lane & 15, koff = (lane >> 4) * 8;
    f32x4 acc[2][8] = {};
    f32x4 accx[2] = {};                   // extra 16 cols (el|er), wc==0 waves only

    int ar = t >> 2, ac = (t & 3) * 8;
    const float* ap = A + (size_t)(m0 + ar) * 256 + ac;
    bool aok = (m0 + ar) < M;

    float4 a0 = make_float4(0.f, 0.f, 0.f, 0.f), a1 = a0;
    if (aok) { a0 = *reinterpret_cast<const float4*>(ap); a1 = *reinterpret_cast<const float4*>(ap + 4); }
    {
        short8 bb;
        bb[0] = (short)f2b(a0.x); bb[1] = (short)f2b(a0.y); bb[2] = (short)f2b(a0.z); bb[3] = (short)f2b(a0.w);
        bb[4] = (short)f2b(a1.x); bb[5] = (short)f2b(a1.y); bb[6] = (short)f2b(a1.z); bb[7] = (short)f2b(a1.w);
        *reinterpret_cast<short8*>(&Asm[0][ar][ac]) = bb;
    }
    __syncthreads();

    for (int kt = 0; kt < 8; ++kt) {
        if (kt < 7) {
            a0 = make_float4(0.f, 0.f, 0.f, 0.f); a1 = a0;
            if (aok) {
                const float* p = ap + (kt + 1) * 32;
                a0 = *reinterpret_cast<const float4*>(p);
                a1 = *reinterpret_cast<const float4*>(p + 4);
            }
        }
        // B fragments direct from L2-resident BTile (contiguous 16B per lane)
        const unsigned short* bkt = BTile + (size_t)kt * 8192;
        short8 a[2], b[8];
#pragma unroll
        for (int ni = 0; ni < 8; ni++)
            b[ni] = *reinterpret_cast<const short8*>(bkt + (size_t)(wc * 128 + ni * 16 + rsub) * 32 + koff);
#pragma unroll
        for (int mi = 0; mi < 2; mi++)
            a[mi] = *reinterpret_cast<const short8*>(&Asm[kt & 1][wr * 32 + mi * 16 + rsub][koff]);
#pragma unroll
        for (int mi = 0; mi < 2; mi++)
#pragma unroll
            for (int ni = 0; ni < 8; ni++)
                acc[mi][ni] = __builtin_amdgcn_mfma_f32_16x16x32_bf16(a[mi], b[ni], acc[mi][ni], 0, 0, 0);
        if (wc == 0) {
            short8 bx = *reinterpret_cast<const short8*>(wlr + (size_t)kt * 512 + rsub * 32 + koff);
#pragma unroll
            for (int mi = 0; mi < 2; mi++)
                accx[mi] = __builtin_amdgcn_mfma_f32_16x16x32_bf16(a[mi], bx, accx[mi], 0, 0, 0);
        }
        if (kt < 7) {
            int nb2 = (kt + 1) & 1;
            short8 bb;
            bb[0] = (short)f2b(a0.x); bb[1] = (short)f2b(a0.y); bb[2] = (short)f2b(a0.z); bb[3] = (short)f2b(a0.w);
            bb[4] = (short)f2b(a1.x); bb[5] = (short)f2b(a1.y); bb[6] = (short)f2b(a1.z); bb[7] = (short)f2b(a1.w);
            __syncthreads();
            *reinterpret_cast<short8*>(&Asm[nb2][ar][ac]) = bb;
            __syncthreads();
        }
    }

    int rgrp = (lane >> 4) * 4, csub = lane & 15;
#pragma unroll
    for (int mi = 0; mi < 2; mi++) {
#pragma unroll
        for (int i = 0; i < 4; i++) {
            int r = m0 + wr * 32 + mi * 16 + rgrp + i;
            if (r < M) {
                int d0 = __builtin_amdgcn_cvt_pk_fp8_f32(acc[mi][0][i], acc[mi][1][i], 0, false);
                d0 = __builtin_amdgcn_cvt_pk_fp8_f32(acc[mi][2][i], acc[mi][3][i], d0, true);
                int d1 = __builtin_amdgcn_cvt_pk_fp8_f32(acc[mi][4][i], acc[mi][5][i], 0, false);
                d1 = __builtin_amdgcn_cvt_pk_fp8_f32(acc[mi][6][i], acc[mi][7][i], d1, true);
                uint2 st; st.x = (unsigned)d0; st.y = (unsigned)d1;
                *reinterpret_cast<uint2*>(F8 + (size_t)r * 256 + wc * 128 + csub * 8) = st;
                if (wc == 0) {
                    float v = accx[mi][i];
                    if (csub < 8) el[r * 8 + csub] = v;
                    else          er[r * 8 + (csub - 8)] = v;
                }
            }
        }
    }
}

// ---------------- GEMM2 (MFMA bf16) + fused el2/er2 -> packed fp8 feat2q8[M,40] ------
__global__ __launch_bounds__(256) void gemm2_mfma(const unsigned short* __restrict__ A,
                                                  const unsigned short* __restrict__ BT,
                                                  const float* __restrict__ al2,
                                                  const float* __restrict__ ar2,
                                                  unsigned char* __restrict__ C8,
                                                  float* __restrict__ el2,
                                                  float* __restrict__ er2, int M) {
    __shared__ unsigned short Asm[2][64][40];
    int t = threadIdx.x;
    int lane = t & 63, w = t >> 6;        // wave tile: 16 rows x 48 cols
    int m0 = blockIdx.x * 64;
    int rsub = lane & 15, koff = (lane >> 4) * 8;
    f32x4 acc[3] = {};

    int r_t = t >> 2, c8 = (t & 3) * 8;
    const unsigned short* ap = A + (size_t)(m0 + r_t) * 256 + c8;
    bool arow_ok = (m0 + r_t) < M;

    uint4 s0 = make_uint4(0, 0, 0, 0);
    if (arow_ok) s0 = *reinterpret_cast<const uint4*>(ap);
    *reinterpret_cast<uint4*>(&Asm[0][r_t][c8]) = s0;
    __syncthreads();

    for (int kt = 0; kt < 8; ++kt) {
        if (kt < 7) {
            s0 = make_uint4(0, 0, 0, 0);
            if (arow_ok) s0 = *reinterpret_cast<const uint4*>(ap + (kt + 1) * 32);
        }
        short8 b[3], a;
#pragma unroll
        for (int ni = 0; ni < 3; ni++)
            b[ni] = *reinterpret_cast<const short8*>(BT + (size_t)(ni * 16 + rsub) * 256 + kt * 32 + koff);
        a = *reinterpret_cast<const short8*>(&Asm[kt & 1][w * 16 + rsub][koff]);
#pragma unroll
        for (int ni = 0; ni < 3; ni++)
            acc[ni] = __builtin_amdgcn_mfma_f32_16x16x32_bf16(a, b[ni], acc[ni], 0, 0, 0);
        if (kt < 7) {
            *reinterpret_cast<uint4*>(&Asm[(kt + 1) & 1][r_t][c8]) = s0;
            __syncthreads();
        }
    }

    int rgrp = (lane >> 4) * 4, csub = lane & 15;
    float alc[3], arc[3];
#pragma unroll
    for (int ni = 0; ni < 3; ni++) {
        int col = ni * 16 + csub;
        alc[ni] = (col < 40) ? al2[col] : 0.f;
        arc[ni] = (col < 40) ? ar2[col] : 0.f;
    }
#pragma unroll
    for (int i = 0; i < 4; i++) {
        int r = m0 + w * 16 + rgrp + i;
        float pl = acc[0][i] * alc[0] + acc[1][i] * alc[1] + acc[2][i] * alc[2];
        float pr = acc[0][i] * arc[0] + acc[1][i] * arc[1] + acc[2][i] * arc[2];
        pl += __shfl_xor(pl, 1); pl += __shfl_xor(pl, 2);
        pl += __shfl_xor(pl, 4); pl += __shfl_xor(pl, 8);
        pr += __shfl_xor(pr, 1); pr += __shfl_xor(pr, 2);
        pr += __shfl_xor(pr, 4); pr += __shfl_xor(pr, 8);
        if (r < M) {
#pragma unroll
            for (int ni = 0; ni < 3; ni++) {
                int col = ni * 16 + csub;
                if (col < 40) C8[(size_t)r * 40 + col] = f2e4m3(acc[ni][i]);
            }
            if (csub == 0) { el2[r] = pl; er2[r] = pr; }
        }
    }
}

// ---------------- CSR build: scan ----------------
__global__ void scan1_k(const int* __restrict__ deg, int* __restrict__ offs,
                        int* __restrict__ bsum, int n) {
    __shared__ int s[256];
    int tid = threadIdx.x;
    int i = blockIdx.x * 256 + tid;
    int v = (i < n) ? deg[i] : 0;
    s[tid] = v;
    __syncthreads();
    for (int d = 1; d < 256; d <<= 1) {
        int t = (tid >= d) ? s[tid - d] : 0;
        __syncthreads();
        s[tid] += t;
        __syncthreads();
    }
    if (i < n) offs[i] = s[tid] - v;
    if (tid == 255) bsum[blockIdx.x] = s[255];
}

__global__ void scan3_k(int* __restrict__ offs, const int* __restrict__ bsum,
                        int n, int nb) {
    __shared__ int red[256];
    int tid = threadIdx.x;
    int v = (tid < blockIdx.x && tid < nb) ? bsum[tid] : 0;
    red[tid] = v;
    __syncthreads();
#pragma unroll
    for (int d = 128; d > 0; d >>= 1) {
        if (tid < d) red[tid] += red[tid + d];
        __syncthreads();
    }
    int prefix = red[0];
    int i = blockIdx.x * 256 + tid;
    if (i < n) offs[i] += prefix;
    if (i == 0) offs[n] = N_EDGES;
}

// ---------------- layer-1 attention aggregate (single softmax pass, r11 form) ------
__global__ __launch_bounds__(256) void agg1_k(const unsigned char* __restrict__ feat8,
                                              const float* __restrict__ el,
                                              const float* __restrict__ er,
                                              const int* __restrict__ offs,
                                              const int* __restrict__ ssorted,
                                              unsigned short* __restrict__ h1) {
    __shared__ float sa[4][CAP1 * 8];
    __shared__ int   ss[4][CAP1];
    int t = threadIdx.x;
    int wv = t >> 6, lane = t & 63;
    int n = blockIdx.x * 4 + wv;
    if (n >= N_NODES) return;
    int beg = offs[n];
    int deg = offs[n + 1] - beg;
    int eloc = lane >> 3, h = lane & 7;
    int h0 = (lane >> 5) * 4 + 2 * (lane & 1);
    float er_h = er[n * 8 + h];

    float acc0 = 0.f, acc1 = 0.f, acc2 = 0.f, acc3 = 0.f;

    if (deg <= CAP1) {
        // phase 1: ee -> LDS, per-lane ssum; 4x unrolled for MLP
        float ssum = 0.f;
        int c0 = 0;
        for (; c0 + 32 <= deg; c0 += 32) {
#pragma unroll
            for (int q = 0; q < 4; q++) {
                int idx = c0 + q * 8 + eloc;
                int s = ssorted[beg + idx];
                if (h == 0) ss[wv][idx] = s;
                float ee = __expf(leaky(el[s * 8 + h] + er_h));
                sa[wv][idx * 8 + h] = ee;
                ssum += ee;
            }
        }
        for (; c0 < deg; c0 += 8) {
            int idx = c0 + eloc;
            if (idx < deg) {
                int s = ssorted[beg + idx];
                if (h == 0) ss[wv][idx] = s;
                float ee = __expf(leaky(el[s * 8 + h] + er_h));
                sa[wv][idx * 8 + h] = ee;
                ssum += ee;
            }
        }
        // one reduce over edge-slots -> per-head ssum
        ssum += __shfl_xor(ssum, 8);
        ssum += __shfl_xor(ssum, 16);
        ssum += __shfl_xor(ssum, 32);
        float inv = 1.f / ssum;
        float iv0 = __shfl(inv, h0), iv1 = __shfl(inv, h0 + 1);
        asm volatile("s_waitcnt lgkmcnt(0)" ::: "memory");
        // phase 2: 32-edge batches, unnormalized weights from LDS
        for (c0 = 0; c0 < deg; c0 += 32) {
            int nr = deg - c0; if (nr > 32) nr = 32;
            unsigned u[32];
#pragma unroll
            for (int j = 0; j < 32; j++) {
                if (j < nr) {
                    int sj = ss[wv][c0 + j];
                    u[j] = *reinterpret_cast<const unsigned*>(feat8 + (size_t)sj * 256 + 4 * lane);
                }
            }
#pragma unroll
            for (int j = 0; j < 32; j++) {
                if (j < nr) {
                    float2 av = *reinterpret_cast<const float2*>(&sa[wv][(c0 + j) * 8 + h0]);
                    floatx2 lo = __builtin_amdgcn_cvt_pk_f32_fp8((int)u[j], false);
                    floatx2 hi = __builtin_amdgcn_cvt_pk_f32_fp8((int)u[j], true);
                    acc0 += av.x * lo.x;
                    acc1 += av.x * lo.y;
                    acc2 += av.y * hi.x;
                    acc3 += av.y * hi.y;
                }
            }
        }
        acc0 *= iv0; acc1 *= iv0; acc2 *= iv1; acc3 *= iv1;
    } else {
        // fallback (deg > CAP1): recompute alphas, inline normalization
        float ssum = 0.f;
        for (int c0 = 0; c0 < deg; c0 += 8) {
            bool act = (c0 + eloc) < deg;
            float ee = 0.f;
            if (act) {
                int s = ssorted[beg + c0 + eloc];
                ee = __expf(leaky(el[s * 8 + h] + er_h));
            }
            ssum += ee;
        }
        ssum += __shfl_xor(ssum, 8);
        ssum += __shfl_xor(ssum, 16);
        ssum += __shfl_xor(ssum, 32);
        float inv = 1.f / ssum;
        float iv0 = __shfl(inv, h0), iv1 = __shfl(inv, h0 + 1);
        for (int c0 = 0; c0 < deg; c0 += 8) {
            int nr = deg - c0; if (nr > 8) nr = 8;
            int s = 0; float a = 0.f;
            if (eloc < nr) {
                s = ssorted[beg + c0 + eloc];
                a = __expf(leaky(el[s * 8 + h] + er_h));
            }
#pragma unroll
            for (int j = 0; j < 8; j++) {
                if (j < nr) {
                    int   sj = __shfl(s, j * 8);
                    float a0 = __shfl(a, j * 8 + h0) * iv0;
                    float a1 = __shfl(a, j * 8 + h0 + 1) * iv1;
                    unsigned u = *reinterpret_cast<const unsigned*>(feat8 + (size_t)sj * 256 + 4 * lane);
                    floatx2 lo = __builtin_amdgcn_cvt_pk_f32_fp8((int)u, false);
                    floatx2 hi = __builtin_amdgcn_cvt_pk_f32_fp8((int)u, true);
                    acc0 += a0 * lo.x;
                    acc1 += a0 * lo.y;
                    acc2 += a1 * hi.x;
                    acc3 += a1 * hi.y;
                }
            }
        }
    }
    ushort4 o;
    o.x = f2b(fmaxf(acc0, 0.f));
    o.y = f2b(fmaxf(acc1, 0.f));
    o.z = f2b(fmaxf(acc2, 0.f));
    o.w = f2b(fmaxf(acc3, 0.f));
    *reinterpret_cast<ushort4*>(h1 + (size_t)n * 256 + 4 * lane) = o;
}

// ---------------- layer-2 attention aggregate + log_softmax (fp8 40-col rows) ------
__global__ __launch_bounds__(256) void agg2_k(const unsigned char* __restrict__ feat2q8,
                                              const float* __restrict__ el2,
                                              const float* __restrict__ er2,
                                              const int* __restrict__ offs,
                                              const int* __restrict__ ssorted,
                                              float* __restrict__ out) {
    __shared__ float sa[4][CAP2];
    __shared__ int   ss[4][CAP2];
    int t = threadIdx.x;
    int wv = t >> 6, lane = t & 63;
    int n = blockIdx.x * 4 + wv;
    if (n >= N_NODES) return;
    int beg = offs[n];
    int deg = offs[n + 1] - beg;
    float ern = er2[n];
    int eloc = lane >> 3, c8 = lane & 7;

    float acc[8] = {};
    if (deg <= CAP2) {
        float ssum = 0.f;
        for (int c0 = 0; c0 < deg; c0 += 64) {
            int idx = c0 + lane;
            if (idx < deg) {
                int s = ssorted[beg + idx];
                ss[wv][idx] = s;
                float ee = __expf(leaky(el2[s] + ern));
                sa[wv][idx] = ee;
                ssum += ee;
            }
        }
#pragma unroll
        for (int d = 1; d < 64; d <<= 1) ssum += __shfl_xor(ssum, d);
        float inv = 1.f / ssum;
        asm volatile("s_waitcnt lgkmcnt(0)" ::: "memory");
        for (int c0 = 0; c0 < deg; c0 += 32) {
            uint2 v[4]; float wgt[4];
#pragma unroll
            for (int q = 0; q < 4; q++) {
                int idx = c0 + q * 8 + eloc;
                v[q] = make_uint2(0, 0); wgt[q] = 0.f;
                if (c8 < 5 && idx < deg) {
                    int s = ss[wv][idx]; wgt[q] = sa[wv][idx];
                    v[q] = *reinterpret_cast<const uint2*>(feat2q8 + (size_t)s * 40 + c8 * 8);
                }
            }
#pragma unroll
            for (int q = 0; q < 4; q++) {
                floatx2 f0 = __builtin_amdgcn_cvt_pk_f32_fp8((int)v[q].x, false);
                floatx2 f1 = __builtin_amdgcn_cvt_pk_f32_fp8((int)v[q].x, true);
                floatx2 f2 = __builtin_amdgcn_cvt_pk_f32_fp8((int)v[q].y, false);
                floatx2 f3 = __builtin_amdgcn_cvt_pk_f32_fp8((int)v[q].y, true);
                acc[0] += wgt[q] * f0.x; acc[1] += wgt[q] * f0.y;
                acc[2] += wgt[q] * f1.x; acc[3] += wgt[q] * f1.y;
                acc[4] += wgt[q] * f2.x; acc[5] += wgt[q] * f2.y;
                acc[6] += wgt[q] * f3.x; acc[7] += wgt[q] * f3.y;
            }
        }
#pragma unroll
        for (int i = 0; i < 8; i++) acc[i] *= inv;
    } else {
        float ssum = 0.f;
        for (int c0 = 0; c0 < deg; c0 += 64) {
            bool act = (c0 + lane) < deg;
            if (act) ssum += __expf(leaky(el2[ssorted[beg + c0 + lane]] + ern));
        }
#pragma unroll
        for (int d = 1; d < 64; d <<= 1) ssum += __shfl_xor(ssum, d);
        float inv = 1.f / ssum;
        for (int c0 = 0; c0 < deg; c0 += 8) {
            int nr = deg - c0; if (nr > 8) nr = 8;
            if (eloc < nr && c8 < 5) {
                int s = ssorted[beg + c0 + eloc];
                float a = __expf(leaky(el2[s] + ern)) * inv;
                uint2 v = *reinterpret_cast<const uint2*>(feat2q8 + (size_t)s * 40 + c8 * 8);
                floatx2 f0 = __builtin_amdgcn_cvt_pk_f32_fp8((int)v.x, false);
                floatx2 f1 = __builtin_amdgcn_cvt_pk_f32_fp8((int)v.x, true);
                floatx2 f2 = __builtin_amdgcn_cvt_pk_f32_fp8((int)v.y, false);
                floatx2 f3 = __builtin_amdgcn_cvt_pk_f32_fp8((int)v.y, true);
                acc[0] += a * f0.x; acc[1] += a * f0.y;
                acc[2] += a * f1.x; acc[3] += a * f1.y;
                acc[4] += a * f2.x; acc[5] += a * f2.y;
                acc[6] += a * f3.x; acc[7] += a * f3.y;
            }
        }
    }
#pragma unroll
    for (int i = 0; i < 8; i++) {
        acc[i] += __shfl_xor(acc[i], 8);
        acc[i] += __shfl_xor(acc[i], 16);
        acc[i] += __shfl_xor(acc[i], 32);
    }
    float lmax = -INFINITY;
    if (c8 < 5) {
#pragma unroll
        for (int i = 0; i < 8; i++) lmax = fmaxf(lmax, acc[i]);
    }
    lmax = fmaxf(lmax, __shfl_xor(lmax, 1));
    lmax = fmaxf(lmax, __shfl_xor(lmax, 2));
    lmax = fmaxf(lmax, __shfl_xor(lmax, 4));
    float lsum = 0.f;
    if (c8 < 5) {
#pragma unroll
        for (int i = 0; i < 8; i++) lsum += __expf(acc[i] - lmax);
    }
    lsum += __shfl_xor(lsum, 1);
    lsum += __shfl_xor(lsum, 2);
    lsum += __shfl_xor(lsum, 4);
    if (eloc == 0 && c8 < 5) {
        float lg = __logf(lsum);
        float* o = out + (size_t)n * 40 + c8 * 8;
#pragma unroll
        for (int i = 0; i < 8; i++) o[i] = acc[i] - lmax - lg;
    }
}

extern "C" void kernel_launch(void* const* d_in, const int* in_sizes, int n_in,
                              void* d_out, int out_size, void* d_ws, size_t ws_size,
                              hipStream_t stream) {
    (void)in_sizes; (void)n_in; (void)out_size; (void)ws_size;
    const float* x   = (const float*)d_in[0];
    const int*   src = (const int*)d_in[1];
    const int*   dst = (const int*)d_in[2];
    const float* W1  = (const float*)d_in[3];
    const float* al1 = (const float*)d_in[4];
    const float* ar1 = (const float*)d_in[5];
    const float* W2  = (const float*)d_in[6];
    const float* al2 = (const float*)d_in[7];
    const float* ar2 = (const float*)d_in[8];
    float* out = (float*)d_out;

    char* ws = (char*)d_ws;
    size_t off = 0;
    auto alloc = [&](size_t bytes) {
        void* p = ws + off;
        off += (bytes + 255) & ~(size_t)255;
        return p;
    };
    unsigned short* w1tile  = (unsigned short*)alloc((size_t)8 * 256 * 32 * 2);
    unsigned short* w2t     = (unsigned short*)alloc((size_t)48 * 256 * 2);
    unsigned short* wlr     = (unsigned short*)alloc((size_t)8 * 16 * 32 * 2);
    unsigned char*  feat8   = (unsigned char*)alloc((size_t)N_NODES * 256);
    unsigned short* h1p     = (unsigned short*)alloc((size_t)N_NODES * 256 * 2);
    unsigned char*  feat2q8 = (unsigned char*)alloc((size_t)N_NODES * 40);
    float* el1   = (float*)alloc((size_t)N_NODES * 8 * 4);
    float* er1   = (float*)alloc((size_t)N_NODES * 8 * 4);
    float* el2   = (float*)alloc((size_t)N_NODES * 4);
    float* er2   = (float*)alloc((size_t)N_NODES * 4);
    int* deg     = (int*)alloc((size_t)N_NODES * 4);
    int* offs    = (int*)alloc((size_t)(N_NODES + 1) * 4);
    int* rank    = (int*)alloc((size_t)N_EDGES * 4);
    int* bsum    = (int*)alloc(1024 * 4);
    int* ssorted = (int*)alloc((size_t)N_EDGES * 4);

    hipMemsetAsync(deg, 0, (size_t)N_NODES * 4, stream);

    // fused weight conversion + Wl/Wr fold + degree histogram with rank capture
    cvt_hist_k<<<257 + (N_EDGES / 4 + 255) / 256, 256, 0, stream>>>(W1, W2, al1, ar1,
                                                                    w1tile, w2t, wlr, dst, deg, rank);
    int nb = (N_NODES + 255) / 256;   // 196 <= 256
    scan1_k<<<nb, 256, 0, stream>>>(deg, offs, bsum, N_NODES);
    scan3_k<<<nb, 256, 0, stream>>>(offs, bsum, N_NODES, nb);

    // layer 1: gemm tiles first, then scatter blocks (drain under gemm compute)
    int gblocks = (N_NODES + 63) / 64;             // 782
    int sblocks = (N_EDGES / 4 + 255) / 256;       // 782
    gemm1_scatter_k<<<gblocks + sblocks, 256, 0, stream>>>(x, w1tile, wlr, feat8, el1, er1,
                                                           N_NODES, gblocks,
                                                           src, dst, rank, offs, ssorted);
    agg1_k<<<(N_NODES + 3) / 4, 256, 0, stream>>>(feat8, el1, er1, offs, ssorted, h1p);

    // layer 2
    gemm2_mfma<<<(N_NODES + 63) / 64, 256, 0, stream>>>(h1p, w2t, al2, ar2, feat2q8, el2, er2, N_NODES);
    agg2_k<<<(N_NODES + 3) / 4, 256, 0, stream>>>(feat2q8, el2, er2, offs, ssorted, out);
}

// Round 18
// 178.756 us; speedup vs baseline: 1.0569x; 1.0569x over previous
//
#include <hip/hip_runtime.h>
#include <hip/hip_bf16.h>
#include <math.h>

#define N_NODES 50000
#define N_EDGES 800000
#define IN_DIM  256
#define HID     32
#define HEADS   8
#define NCLS    40
#define NEG     0.2f
#define CAP1    128
#define CAP2    128

using short8  = __attribute__((ext_vector_type(8))) short;
using f32x4   = __attribute__((ext_vector_type(4))) float;
using floatx2 = __attribute__((ext_vector_type(2))) float;

__device__ __forceinline__ float leaky(float x) { return x >= 0.f ? x : NEG * x; }
__device__ __forceinline__ unsigned short f2b(float f) {
    unsigned int u = __float_as_uint(f);
    unsigned int r = (u + 0x7fffu + ((u >> 16) & 1u)) >> 16;
    return (unsigned short)r;
}
__device__ __forceinline__ float b2f(unsigned short h) {
    return __uint_as_float((unsigned int)h << 16);
}
__device__ __forceinline__ unsigned char f2e4m3(float v) {
    int p = __builtin_amdgcn_cvt_pk_fp8_f32(v, v, 0, false);
    return (unsigned char)(p & 0xff);
}

// Permuted fp8/bf16 channel storage: channel c = half*128 + ni*16 + csub
// stored at offset s = half*128 + csub*8 + ni.

// Fused: weight conversion (blocks 0..255) + Wl/Wr fold (block 256) + histogram+rank (rest)
__global__ void cvt_hist_k(const float* __restrict__ W1, const float* __restrict__ W2,
                           const float* __restrict__ al1, const float* __restrict__ ar1,
                           unsigned short* __restrict__ BTile, unsigned short* __restrict__ W2T,
                           unsigned short* __restrict__ wlr,
                           const int* __restrict__ dst, int* __restrict__ deg,
                           int* __restrict__ rank) {
    if (blockIdx.x < 256) {
        int n = blockIdx.x, k = threadIdx.x;
        BTile[(size_t)(k >> 5) * 8192 + n * 32 + (k & 31)] = f2b(W1[k * 256 + n]);
        if (n < 48) {
            int half = k >> 7, cs = (k & 127) >> 3, ni = k & 7;
            int ck = half * 128 + ni * 16 + cs;
            W2T[n * 256 + k] = (n < 40) ? f2b(W2[ck * 40 + n]) : (unsigned short)0;
        }
    } else if (blockIdx.x == 256) {
        int k = threadIdx.x;                      // 0..255
        const float* wrow = W1 + (size_t)k * 256;
#pragma unroll
        for (int h = 0; h < 8; h++) {
            float vl = 0.f, vr = 0.f;
#pragma unroll
            for (int d = 0; d < 32; d++) {
                float w = wrow[h * 32 + d];
                vl += w * al1[h * 32 + d];
                vr += w * ar1[h * 32 + d];
            }
            wlr[(size_t)(k >> 5) * 512 + h * 32 + (k & 31)]        = f2b(vl);
            wlr[(size_t)(k >> 5) * 512 + (8 + h) * 32 + (k & 31)]  = f2b(vr);
        }
    } else {
        int e4 = (blockIdx.x - 257) * 256 + threadIdx.x;
        if (e4 * 4 >= N_EDGES) return;
        int4 d = *reinterpret_cast<const int4*>(dst + e4 * 4);
        int4 rk;
        rk.x = atomicAdd(&deg[d.x], 1);
        rk.y = atomicAdd(&deg[d.y], 1);
        rk.z = atomicAdd(&deg[d.z], 1);
        rk.w = atomicAdd(&deg[d.w], 1);
        *reinterpret_cast<int4*>(rank + e4 * 4) = rk;
    }
}

// ---------------- GEMM1 (MFMA bf16, A+B LDS dbuf) + el1/er1 + trailing scatter ------
// blocks [0, gblocks): GEMM1 64-row tiles
// blocks [gblocks, ...): ssorted[offs[d]+rank[e]] = src[e]  (fire-and-forget)
__global__ __launch_bounds__(256) void gemm1_scatter_k(const float* __restrict__ A,
                                                       const unsigned short* __restrict__ BTile,
                                                       const unsigned short* __restrict__ wlr,
                                                       unsigned char* __restrict__ F8,
                                                       float* __restrict__ el,
                                                       float* __restrict__ er, int M,
                                                       int gblocks,
                                                       const int* __restrict__ src,
                                                       const int* __restrict__ dst,
                                                       const int* __restrict__ rank,
                                                       const int* __restrict__ offs,
                                                       int* __restrict__ ssorted) {
    __shared__ unsigned short Asm[2][64][40];
    __shared__ unsigned short Bsm[2][256][40];
    if (blockIdx.x >= gblocks) {
        int e4 = (blockIdx.x - gblocks) * 256 + threadIdx.x;
        if (e4 * 4 >= N_EDGES) return;
        int4 d  = *reinterpret_cast<const int4*>(dst + e4 * 4);
        int4 sv = *reinterpret_cast<const int4*>(src + e4 * 4);
        int4 rk = *reinterpret_cast<const int4*>(rank + e4 * 4);
        __builtin_nontemporal_store(sv.x, &ssorted[offs[d.x] + rk.x]);
        __builtin_nontemporal_store(sv.y, &ssorted[offs[d.y] + rk.y]);
        __builtin_nontemporal_store(sv.z, &ssorted[offs[d.z] + rk.z]);
        __builtin_nontemporal_store(sv.w, &ssorted[offs[d.w] + rk.w]);
        return;
    }
    int t = threadIdx.x;
    int lane = t & 63, w = t >> 6;
    int wr = w >> 1, wc = w & 1;          // wave tile: 32 rows x 128 cols
    int m0 = blockIdx.x * 64;
    int rsub = lane & 15, koff = (lane >> 4) * 8;
    f32x4 acc[2][8] = {};
    f32x4 accx[2] = {};                   // extra 16 cols (el|er), wc==0 waves only

    int ar = t >> 2, ac = (t & 3) * 8;
    const float* ap = A + (size_t)(m0 + ar) * 256 + ac;
    bool aok = (m0 + ar) < M;
    const unsigned short* bp = BTile + (size_t)t * 32;

    float4 a0 = make_float4(0.f, 0.f, 0.f, 0.f), a1 = a0;
    if (aok) { a0 = *reinterpret_cast<const float4*>(ap); a1 = *reinterpret_cast<const float4*>(ap + 4); }
    uint4 b0 = *reinterpret_cast<const uint4*>(bp);
    uint4 b1 = *reinterpret_cast<const uint4*>(bp + 8);
    uint4 b2 = *reinterpret_cast<const uint4*>(bp + 16);
    uint4 b3 = *reinterpret_cast<const uint4*>(bp + 24);
    {
        short8 bb;
        bb[0] = (short)f2b(a0.x); bb[1] = (short)f2b(a0.y); bb[2] = (short)f2b(a0.z); bb[3] = (short)f2b(a0.w);
        bb[4] = (short)f2b(a1.x); bb[5] = (short)f2b(a1.y); bb[6] = (short)f2b(a1.z); bb[7] = (short)f2b(a1.w);
        *reinterpret_cast<short8*>(&Asm[0][ar][ac]) = bb;
        *reinterpret_cast<uint4*>(&Bsm[0][t][0])  = b0;
        *reinterpret_cast<uint4*>(&Bsm[0][t][8])  = b1;
        *reinterpret_cast<uint4*>(&Bsm[0][t][16]) = b2;
        *reinterpret_cast<uint4*>(&Bsm[0][t][24]) = b3;
    }
    __syncthreads();

    for (int kt = 0; kt < 8; ++kt) {
        if (kt < 7) {
            a0 = make_float4(0.f, 0.f, 0.f, 0.f); a1 = a0;
            if (aok) {
                const float* p = ap + (kt + 1) * 32;
                a0 = *reinterpret_cast<const float4*>(p);
                a1 = *reinterpret_cast<const float4*>(p + 4);
            }
            const unsigned short* nb = bp + (size_t)(kt + 1) * 8192;
            b0 = *reinterpret_cast<const uint4*>(nb);
            b1 = *reinterpret_cast<const uint4*>(nb + 8);
            b2 = *reinterpret_cast<const uint4*>(nb + 16);
            b3 = *reinterpret_cast<const uint4*>(nb + 24);
        }
        short8 a[2], b[8];
#pragma unroll
        for (int mi = 0; mi < 2; mi++)
            a[mi] = *reinterpret_cast<const short8*>(&Asm[kt & 1][wr * 32 + mi * 16 + rsub][koff]);
#pragma unroll
        for (int ni = 0; ni < 8; ni++)
            b[ni] = *reinterpret_cast<const short8*>(&Bsm[kt & 1][wc * 128 + ni * 16 + rsub][koff]);
#pragma unroll
        for (int mi = 0; mi < 2; mi++)
#pragma unroll
            for (int ni = 0; ni < 8; ni++)
                acc[mi][ni] = __builtin_amdgcn_mfma_f32_16x16x32_bf16(a[mi], b[ni], acc[mi][ni], 0, 0, 0);
        if (wc == 0) {
            short8 bx = *reinterpret_cast<const short8*>(wlr + (size_t)kt * 512 + rsub * 32 + koff);
#pragma unroll
            for (int mi = 0; mi < 2; mi++)
                accx[mi] = __builtin_amdgcn_mfma_f32_16x16x32_bf16(a[mi], bx, accx[mi], 0, 0, 0);
        }
        if (kt < 7) {
            int nb2 = (kt + 1) & 1;
            short8 bb;
            bb[0] = (short)f2b(a0.x); bb[1] = (short)f2b(a0.y); bb[2] = (short)f2b(a0.z); bb[3] = (short)f2b(a0.w);
            bb[4] = (short)f2b(a1.x); bb[5] = (short)f2b(a1.y); bb[6] = (short)f2b(a1.z); bb[7] = (short)f2b(a1.w);
            *reinterpret_cast<short8*>(&Asm[nb2][ar][ac]) = bb;
            *reinterpret_cast<uint4*>(&Bsm[nb2][t][0])  = b0;
            *reinterpret_cast<uint4*>(&Bsm[nb2][t][8])  = b1;
            *reinterpret_cast<uint4*>(&Bsm[nb2][t][16]) = b2;
            *reinterpret_cast<uint4*>(&Bsm[nb2][t][24]) = b3;
            __syncthreads();
        }
    }

    int rgrp = (lane >> 4) * 4, csub = lane & 15;
#pragma unroll
    for (int mi = 0; mi < 2; mi++) {
#pragma unroll
        for (int i = 0; i < 4; i++) {
            int r = m0 + wr * 32 + mi * 16 + rgrp + i;
            if (r < M) {
                int d0 = __builtin_amdgcn_cvt_pk_fp8_f32(acc[mi][0][i], acc[mi][1][i], 0, false);
                d0 = __builtin_amdgcn_cvt_pk_fp8_f32(acc[mi][2][i], acc[mi][3][i], d0, true);
                int d1 = __builtin_amdgcn_cvt_pk_fp8_f32(acc[mi][4][i], acc[mi][5][i], 0, false);
                d1 = __builtin_amdgcn_cvt_pk_fp8_f32(acc[mi][6][i], acc[mi][7][i], d1, true);
                uint2 st; st.x = (unsigned)d0; st.y = (unsigned)d1;
                *reinterpret_cast<uint2*>(F8 + (size_t)r * 256 + wc * 128 + csub * 8) = st;
                if (wc == 0) {
                    float v = accx[mi][i];
                    if (csub < 8) el[r * 8 + csub] = v;
                    else          er[r * 8 + (csub - 8)] = v;
                }
            }
        }
    }
}

// ---------------- GEMM2 (MFMA bf16) + fused el2/er2 -> packed fp8 feat2q8[M,40] ------
__global__ __launch_bounds__(256) void gemm2_mfma(const unsigned short* __restrict__ A,
                                                  const unsigned short* __restrict__ BT,
                                                  const float* __restrict__ al2,
                                                  const float* __restrict__ ar2,
                                                  unsigned char* __restrict__ C8,
                                                  float* __restrict__ el2,
                                                  float* __restrict__ er2, int M) {
    __shared__ unsigned short Asm[2][64][40];
    int t = threadIdx.x;
    int lane = t & 63, w = t >> 6;        // wave tile: 16 rows x 48 cols
    int m0 = blockIdx.x * 64;
    int rsub = lane & 15, koff = (lane >> 4) * 8;
    f32x4 acc[3] = {};

    int r_t = t >> 2, c8 = (t & 3) * 8;
    const unsigned short* ap = A + (size_t)(m0 + r_t) * 256 + c8;
    bool arow_ok = (m0 + r_t) < M;

    uint4 s0 = make_uint4(0, 0, 0, 0);
    if (arow_ok) s0 = *reinterpret_cast<const uint4*>(ap);
    *reinterpret_cast<uint4*>(&Asm[0][r_t][c8]) = s0;
    __syncthreads();

    for (int kt = 0; kt < 8; ++kt) {
        if (kt < 7) {
            s0 = make_uint4(0, 0, 0, 0);
            if (arow_ok) s0 = *reinterpret_cast<const uint4*>(ap + (kt + 1) * 32);
        }
        short8 b[3], a;
#pragma unroll
        for (int ni = 0; ni < 3; ni++)
            b[ni] = *reinterpret_cast<const short8*>(BT + (size_t)(ni * 16 + rsub) * 256 + kt * 32 + koff);
        a = *reinterpret_cast<const short8*>(&Asm[kt & 1][w * 16 + rsub][koff]);
#pragma unroll
        for (int ni = 0; ni < 3; ni++)
            acc[ni] = __builtin_amdgcn_mfma_f32_16x16x32_bf16(a, b[ni], acc[ni], 0, 0, 0);
        if (kt < 7) {
            *reinterpret_cast<uint4*>(&Asm[(kt + 1) & 1][r_t][c8]) = s0;
            __syncthreads();
        }
    }

    int rgrp = (lane >> 4) * 4, csub = lane & 15;
    float alc[3], arc[3];
#pragma unroll
    for (int ni = 0; ni < 3; ni++) {
        int col = ni * 16 + csub;
        alc[ni] = (col < 40) ? al2[col] : 0.f;
        arc[ni] = (col < 40) ? ar2[col] : 0.f;
    }
#pragma unroll
    for (int i = 0; i < 4; i++) {
        int r = m0 + w * 16 + rgrp + i;
        float pl = acc[0][i] * alc[0] + acc[1][i] * alc[1] + acc[2][i] * alc[2];
        float pr = acc[0][i] * arc[0] + acc[1][i] * arc[1] + acc[2][i] * arc[2];
        pl += __shfl_xor(pl, 1); pl += __shfl_xor(pl, 2);
        pl += __shfl_xor(pl, 4); pl += __shfl_xor(pl, 8);
        pr += __shfl_xor(pr, 1); pr += __shfl_xor(pr, 2);
        pr += __shfl_xor(pr, 4); pr += __shfl_xor(pr, 8);
        if (r < M) {
#pragma unroll
            for (int ni = 0; ni < 3; ni++) {
                int col = ni * 16 + csub;
                if (col < 40) C8[(size_t)r * 40 + col] = f2e4m3(acc[ni][i]);
            }
            if (csub == 0) { el2[r] = pl; er2[r] = pr; }
        }
    }
}

// ---------------- CSR build: scan ----------------
__global__ void scan1_k(const int* __restrict__ deg, int* __restrict__ offs,
                        int* __restrict__ bsum, int n) {
    __shared__ int s[256];
    int tid = threadIdx.x;
    int i = blockIdx.x * 256 + tid;
    int v = (i < n) ? deg[i] : 0;
    s[tid] = v;
    __syncthreads();
    for (int d = 1; d < 256; d <<= 1) {
        int t = (tid >= d) ? s[tid - d] : 0;
        __syncthreads();
        s[tid] += t;
        __syncthreads();
    }
    if (i < n) offs[i] = s[tid] - v;
    if (tid == 255) bsum[blockIdx.x] = s[255];
}

__global__ void scan3_k(int* __restrict__ offs, const int* __restrict__ bsum,
                        int n, int nb) {
    __shared__ int red[256];
    int tid = threadIdx.x;
    int v = (tid < blockIdx.x && tid < nb) ? bsum[tid] : 0;
    red[tid] = v;
    __syncthreads();
#pragma unroll
    for (int d = 128; d > 0; d >>= 1) {
        if (tid < d) red[tid] += red[tid + d];
        __syncthreads();
    }
    int prefix = red[0];
    int i = blockIdx.x * 256 + tid;
    if (i < n) offs[i] += prefix;
    if (i == 0) offs[n] = N_EDGES;
}

// ---------------- layer-1 attention aggregate (single softmax pass, r11 form) ------
__global__ __launch_bounds__(256) void agg1_k(const unsigned char* __restrict__ feat8,
                                              const float* __restrict__ el,
                                              const float* __restrict__ er,
                                              const int* __restrict__ offs,
                                              const int* __restrict__ ssorted,
                                              unsigned short* __restrict__ h1) {
    __shared__ float sa[4][CAP1 * 8];
    __shared__ int   ss[4][CAP1];
    int t = threadIdx.x;
    int wv = t >> 6, lane = t & 63;
    int n = blockIdx.x * 4 + wv;
    if (n >= N_NODES) return;
    int beg = offs[n];
    int deg = offs[n + 1] - beg;
    int eloc = lane >> 3, h = lane & 7;
    int h0 = (lane >> 5) * 4 + 2 * (lane & 1);
    float er_h = er[n * 8 + h];

    float acc0 = 0.f, acc1 = 0.f, acc2 = 0.f, acc3 = 0.f;

    if (deg <= CAP1) {
        // phase 1: ee -> LDS, per-lane ssum; 4x unrolled for MLP
        float ssum = 0.f;
        int c0 = 0;
        for (; c0 + 32 <= deg; c0 += 32) {
#pragma unroll
            for (int q = 0; q < 4; q++) {
                int idx = c0 + q * 8 + eloc;
                int s = ssorted[beg + idx];
                if (h == 0) ss[wv][idx] = s;
                float ee = __expf(leaky(el[s * 8 + h] + er_h));
                sa[wv][idx * 8 + h] = ee;
                ssum += ee;
            }
        }
        for (; c0 < deg; c0 += 8) {
            int idx = c0 + eloc;
            if (idx < deg) {
                int s = ssorted[beg + idx];
                if (h == 0) ss[wv][idx] = s;
                float ee = __expf(leaky(el[s * 8 + h] + er_h));
                sa[wv][idx * 8 + h] = ee;
                ssum += ee;
            }
        }
        // one reduce over edge-slots -> per-head ssum
        ssum += __shfl_xor(ssum, 8);
        ssum += __shfl_xor(ssum, 16);
        ssum += __shfl_xor(ssum, 32);
        float inv = 1.f / ssum;
        float iv0 = __shfl(inv, h0), iv1 = __shfl(inv, h0 + 1);
        asm volatile("s_waitcnt lgkmcnt(0)" ::: "memory");
        // phase 2: 32-edge batches, unnormalized weights from LDS
        for (c0 = 0; c0 < deg; c0 += 32) {
            int nr = deg - c0; if (nr > 32) nr = 32;
            unsigned u[32];
#pragma unroll
            for (int j = 0; j < 32; j++) {
                if (j < nr) {
                    int sj = ss[wv][c0 + j];
                    u[j] = *reinterpret_cast<const unsigned*>(feat8 + (size_t)sj * 256 + 4 * lane);
                }
            }
#pragma unroll
            for (int j = 0; j < 32; j++) {
                if (j < nr) {
                    float2 av = *reinterpret_cast<const float2*>(&sa[wv][(c0 + j) * 8 + h0]);
                    floatx2 lo = __builtin_amdgcn_cvt_pk_f32_fp8((int)u[j], false);
                    floatx2 hi = __builtin_amdgcn_cvt_pk_f32_fp8((int)u[j], true);
                    acc0 += av.x * lo.x;
                    acc1 += av.x * lo.y;
                    acc2 += av.y * hi.x;
                    acc3 += av.y * hi.y;
                }
            }
        }
        acc0 *= iv0; acc1 *= iv0; acc2 *= iv1; acc3 *= iv1;
    } else {
        // fallback (deg > CAP1): recompute alphas, inline normalization
        float ssum = 0.f;
        for (int c0 = 0; c0 < deg; c0 += 8) {
            bool act = (c0 + eloc) < deg;
            float ee = 0.f;
            if (act) {
                int s = ssorted[beg + c0 + eloc];
                ee = __expf(leaky(el[s * 8 + h] + er_h));
            }
            ssum += ee;
        }
        ssum += __shfl_xor(ssum, 8);
        ssum += __shfl_xor(ssum, 16);
        ssum += __shfl_xor(ssum, 32);
        float inv = 1.f / ssum;
        float iv0 = __shfl(inv, h0), iv1 = __shfl(inv, h0 + 1);
        for (int c0 = 0; c0 < deg; c0 += 8) {
            int nr = deg - c0; if (nr > 8) nr = 8;
            int s = 0; float a = 0.f;
            if (eloc < nr) {
                s = ssorted[beg + c0 + eloc];
                a = __expf(leaky(el[s * 8 + h] + er_h));
            }
#pragma unroll
            for (int j = 0; j < 8; j++) {
                if (j < nr) {
                    int   sj = __shfl(s, j * 8);
                    float a0 = __shfl(a, j * 8 + h0) * iv0;
                    float a1 = __shfl(a, j * 8 + h0 + 1) * iv1;
                    unsigned u = *reinterpret_cast<const unsigned*>(feat8 + (size_t)sj * 256 + 4 * lane);
                    floatx2 lo = __builtin_amdgcn_cvt_pk_f32_fp8((int)u, false);
                    floatx2 hi = __builtin_amdgcn_cvt_pk_f32_fp8((int)u, true);
                    acc0 += a0 * lo.x;
                    acc1 += a0 * lo.y;
                    acc2 += a1 * hi.x;
                    acc3 += a1 * hi.y;
                }
            }
        }
    }
    ushort4 o;
    o.x = f2b(fmaxf(acc0, 0.f));
    o.y = f2b(fmaxf(acc1, 0.f));
    o.z = f2b(fmaxf(acc2, 0.f));
    o.w = f2b(fmaxf(acc3, 0.f));
    *reinterpret_cast<ushort4*>(h1 + (size_t)n * 256 + 4 * lane) = o;
}

// ---------------- layer-2 attention aggregate + log_softmax (fp8 40-col rows) ------
__global__ __launch_bounds__(256) void agg2_k(const unsigned char* __restrict__ feat2q8,
                                              const float* __restrict__ el2,
                                              const float* __restrict__ er2,
                                              const int* __restrict__ offs,
                                              const int* __restrict__ ssorted,
                                              float* __restrict__ out) {
    __shared__ float sa[4][CAP2];
    __shared__ int   ss[4][CAP2];
    int t = threadIdx.x;
    int wv = t >> 6, lane = t & 63;
    int n = blockIdx.x * 4 + wv;
    if (n >= N_NODES) return;
    int beg = offs[n];
    int deg = offs[n + 1] - beg;
    float ern = er2[n];
    int eloc = lane >> 3, c8 = lane & 7;

    float acc[8] = {};
    if (deg <= CAP2) {
        float ssum = 0.f;
        for (int c0 = 0; c0 < deg; c0 += 64) {
            int idx = c0 + lane;
            if (idx < deg) {
                int s = ssorted[beg + idx];
                ss[wv][idx] = s;
                float ee = __expf(leaky(el2[s] + ern));
                sa[wv][idx] = ee;
                ssum += ee;
            }
        }
#pragma unroll
        for (int d = 1; d < 64; d <<= 1) ssum += __shfl_xor(ssum, d);
        float inv = 1.f / ssum;
        asm volatile("s_waitcnt lgkmcnt(0)" ::: "memory");
        for (int c0 = 0; c0 < deg; c0 += 32) {
            uint2 v[4]; float wgt[4];
#pragma unroll
            for (int q = 0; q < 4; q++) {
                int idx = c0 + q * 8 + eloc;
                v[q] = make_uint2(0, 0); wgt[q] = 0.f;
                if (c8 < 5 && idx < deg) {
                    int s = ss[wv][idx]; wgt[q] = sa[wv][idx];
                    v[q] = *reinterpret_cast<const uint2*>(feat2q8 + (size_t)s * 40 + c8 * 8);
                }
            }
#pragma unroll
            for (int q = 0; q < 4; q++) {
                floatx2 f0 = __builtin_amdgcn_cvt_pk_f32_fp8((int)v[q].x, false);
                floatx2 f1 = __builtin_amdgcn_cvt_pk_f32_fp8((int)v[q].x, true);
                floatx2 f2 = __builtin_amdgcn_cvt_pk_f32_fp8((int)v[q].y, false);
                floatx2 f3 = __builtin_amdgcn_cvt_pk_f32_fp8((int)v[q].y, true);
                acc[0] += wgt[q] * f0.x; acc[1] += wgt[q] * f0.y;
                acc[2] += wgt[q] * f1.x; acc[3] += wgt[q] * f1.y;
                acc[4] += wgt[q] * f2.x; acc[5] += wgt[q] * f2.y;
                acc[6] += wgt[q] * f3.x; acc[7] += wgt[q] * f3.y;
            }
        }
#pragma unroll
        for (int i = 0; i < 8; i++) acc[i] *= inv;
    } else {
        float ssum = 0.f;
        for (int c0 = 0; c0 < deg; c0 += 64) {
            bool act = (c0 + lane) < deg;
            if (act) ssum += __expf(leaky(el2[ssorted[beg + c0 + lane]] + ern));
        }
#pragma unroll
        for (int d = 1; d < 64; d <<= 1) ssum += __shfl_xor(ssum, d);
        float inv = 1.f / ssum;
        for (int c0 = 0; c0 < deg; c0 += 8) {
            int nr = deg - c0; if (nr > 8) nr = 8;
            if (eloc < nr && c8 < 5) {
                int s = ssorted[beg + c0 + eloc];
                float a = __expf(leaky(el2[s] + ern)) * inv;
                uint2 v = *reinterpret_cast<const uint2*>(feat2q8 + (size_t)s * 40 + c8 * 8);
                floatx2 f0 = __builtin_amdgcn_cvt_pk_f32_fp8((int)v.x, false);
                floatx2 f1 = __builtin_amdgcn_cvt_pk_f32_fp8((int)v.x, true);
                floatx2 f2 = __builtin_amdgcn_cvt_pk_f32_fp8((int)v.y, false);
                floatx2 f3 = __builtin_amdgcn_cvt_pk_f32_fp8((int)v.y, true);
                acc[0] += a * f0.x; acc[1] += a * f0.y;
                acc[2] += a * f1.x; acc[3] += a * f1.y;
                acc[4] += a * f2.x; acc[5] += a * f2.y;
                acc[6] += a * f3.x; acc[7] += a * f3.y;
            }
        }
    }
#pragma unroll
    for (int i = 0; i < 8; i++) {
        acc[i] += __shfl_xor(acc[i], 8);
        acc[i] += __shfl_xor(acc[i], 16);
        acc[i] += __shfl_xor(acc[i], 32);
    }
    float lmax = -INFINITY;
    if (c8 < 5) {
#pragma unroll
        for (int i = 0; i < 8; i++) lmax = fmaxf(lmax, acc[i]);
    }
    lmax = fmaxf(lmax, __shfl_xor(lmax, 1));
    lmax = fmaxf(lmax, __shfl_xor(lmax, 2));
    lmax = fmaxf(lmax, __shfl_xor(lmax, 4));
    float lsum = 0.f;
    if (c8 < 5) {
#pragma unroll
        for (int i = 0; i < 8; i++) lsum += __expf(acc[i] - lmax);
    }
    lsum += __shfl_xor(lsum, 1);
    lsum += __shfl_xor(lsum, 2);
    lsum += __shfl_xor(lsum, 4);
    if (eloc == 0 && c8 < 5) {
        float lg = __logf(lsum);
        float* o = out + (size_t)n * 40 + c8 * 8;
#pragma unroll
        for (int i = 0; i < 8; i++) o[i] = acc[i] - lmax - lg;
    }
}

extern "C" void kernel_launch(void* const* d_in, const int* in_sizes, int n_in,
                              void* d_out, int out_size, void* d_ws, size_t ws_size,
                              hipStream_t stream) {
    (void)in_sizes; (void)n_in; (void)out_size; (void)ws_size;
    const float* x   = (const float*)d_in[0];
    const int*   src = (const int*)d_in[1];
    const int*   dst = (const int*)d_in[2];
    const float* W1  = (const float*)d_in[3];
    const float* al1 = (const float*)d_in[4];
    const float* ar1 = (const float*)d_in[5];
    const float* W2  = (const float*)d_in[6];
    const float* al2 = (const float*)d_in[7];
    const float* ar2 = (const float*)d_in[8];
    float* out = (float*)d_out;

    char* ws = (char*)d_ws;
    size_t off = 0;
    auto alloc = [&](size_t bytes) {
        void* p = ws + off;
        off += (bytes + 255) & ~(size_t)255;
        return p;
    };
    unsigned short* w1tile  = (unsigned short*)alloc((size_t)8 * 256 * 32 * 2);
    unsigned short* w2t     = (unsigned short*)alloc((size_t)48 * 256 * 2);
    unsigned short* wlr     = (unsigned short*)alloc((size_t)8 * 16 * 32 * 2);
    unsigned char*  feat8   = (unsigned char*)alloc((size_t)N_NODES * 256);
    unsigned short* h1p     = (unsigned short*)alloc((size_t)N_NODES * 256 * 2);
    unsigned char*  feat2q8 = (unsigned char*)alloc((size_t)N_NODES * 40);
    float* el1   = (float*)alloc((size_t)N_NODES * 8 * 4);
    float* er1   = (float*)alloc((size_t)N_NODES * 8 * 4);
    float* el2   = (float*)alloc((size_t)N_NODES * 4);
    float* er2   = (float*)alloc((size_t)N_NODES * 4);
    int* deg     = (int*)alloc((size_t)N_NODES * 4);
    int* offs    = (int*)alloc((size_t)(N_NODES + 1) * 4);
    int* rank    = (int*)alloc((size_t)N_EDGES * 4);
    int* bsum    = (int*)alloc(1024 * 4);
    int* ssorted = (int*)alloc((size_t)N_EDGES * 4);

    hipMemsetAsync(deg, 0, (size_t)N_NODES * 4, stream);

    // fused weight conversion + Wl/Wr fold + degree histogram with rank capture
    cvt_hist_k<<<257 + (N_EDGES / 4 + 255) / 256, 256, 0, stream>>>(W1, W2, al1, ar1,
                                                                    w1tile, w2t, wlr, dst, deg, rank);
    int nb = (N_NODES + 255) / 256;   // 196 <= 256
    scan1_k<<<nb, 256, 0, stream>>>(deg, offs, bsum, N_NODES);
    scan3_k<<<nb, 256, 0, stream>>>(offs, bsum, N_NODES, nb);

    // layer 1: gemm tiles first, then trailing scatter blocks
    int gblocks = (N_NODES + 63) / 64;             // 782
    int sblocks = (N_EDGES / 4 + 255) / 256;       // 782
    gemm1_scatter_k<<<gblocks + sblocks, 256, 0, stream>>>(x, w1tile, wlr, feat8, el1, er1,
                                                           N_NODES, gblocks,
                                                           src, dst, rank, offs, ssorted);
    agg1_k<<<(N_NODES + 3) / 4, 256, 0, stream>>>(feat8, el1, er1, offs, ssorted, h1p);

    // layer 2
    gemm2_mfma<<<(N_NODES + 63) / 64, 256, 0, stream>>>(h1p, w2t, al2, ar2, feat2q8, el2, er2, N_NODES);
    agg2_k<<<(N_NODES + 3) / 4, 256, 0, stream>>>(feat2q8, el2, er2, offs, ssorted, out);
}